// Round 6
// baseline (496.585 us; speedup 1.0000x reference)
//
#include <hip/hip_runtime.h>
#include <math.h>

// ---------------------------------------------------------------------------
// LinearNO block, MI355X/gfx950. Inputs fp32 (sniffed; bf16 fallback).
// Interior bf16 MFMA. B=8 N=8192 C=256 H=8 D=32 S=32.
//
// R13 changes vs R12 (FAILED: single-launch MLP raced -- output fp32 rows
// >=32768 clobber the xup bytes holding h while low blocks still read them):
//  * fused_mlp: back to the PROVEN R11 v3 body (BM=128, 4 waves, 32 rows/
//    wave), but ONE 512-block launch with an atomic gate replacing stream
//    serialization: low blocks (even bid, rows<32768, stores hit only dead
//    xm bytes) signal a counter after their final syncthreads (vmcnt
//    drained => all h reads returned); high blocks (odd bid, read the ws
//    copy) spin for counter==256 BEFORE their first global store.
//    2 blocks/CU (LDS 76K x2 = 152K <= 160K, VGPR capped 256 via
//    launch_bounds(256,2)) => all 512 blocks co-resident => no deadlock;
//    parity interleave keeps every XCD's resident set mixed.
//    This restores R12's intended 2 waves/SIMD without the race.
// ---------------------------------------------------------------------------

typedef __attribute__((ext_vector_type(8))) short bf8;
typedef __attribute__((ext_vector_type(4))) float f32x4;
typedef __attribute__((ext_vector_type(4))) unsigned short u16x4;
typedef __attribute__((ext_vector_type(8))) unsigned short u16x8;

__device__ __forceinline__ float b2f(unsigned short x) {
  union { unsigned u; float f; } t; t.u = ((unsigned)x) << 16; return t.f;
}
__device__ __forceinline__ unsigned short f2b(float f) {
  union { float f; unsigned u; } t; t.f = f;
  unsigned r = t.u + 0x7fffu + ((t.u >> 16) & 1u);
  return (unsigned short)(r >> 16);
}
__device__ __forceinline__ float gelu_exact(float x) {
  return 0.5f * x * (1.0f + erff(x * 0.7071067811865475f));
}
// A&S 7.1.26 erf, |eps| <= 1.5e-7 (abs). Much cheaper than libm erff.
__device__ __forceinline__ float erf_fast(float x) {
  float ax = fabsf(x);
  float t = __builtin_amdgcn_rcpf(fmaf(0.3275911f, ax, 1.0f));
  float p = t * fmaf(t, fmaf(t, fmaf(t, fmaf(t, 1.061405429f, -1.453152027f),
                                     1.421413741f), -0.284496736f), 0.254829592f);
  float r = 1.0f - p * __expf(-ax * ax);
  return copysignf(r, x);
}
__device__ __forceinline__ float gelu_fast(float x) {
  return 0.5f * x * (1.0f + erf_fast(x * 0.7071067811865475f));
}

// async global->LDS, 16 B per lane. LDS dest must be base + lane*16.
typedef __attribute__((address_space(1))) const void gas_void;
typedef __attribute__((address_space(3))) void las_void;
__device__ __forceinline__ void gl_lds16(const void* g, void* l) {
  __builtin_amdgcn_global_load_lds((gas_void*)g, (las_void*)l, 16, 0, 0);
}

// --------------------------- dtype sniffer ---------------------------------
__global__ void sniff_kernel(const unsigned* __restrict__ fx, int* __restrict__ flag,
                             unsigned* __restrict__ gate) {
  if (threadIdx.x == 0) {
    int cnt = 0;
    for (int i = 0; i < 64; i++) {
      unsigned e = (fx[i] >> 7) & 0xFFu;
      cnt += (e >= 117u && e <= 130u) ? 1 : 0;
    }
    *flag = (cnt >= 32) ? 1 : 0;   // 1 = bf16 inputs, 0 = fp32
    *gate = 0u;                    // MLP ordering gate (re-zeroed every replay)
  }
}

// --------------------------- weight table ----------------------------------
struct CvtDesc { const void* src[15]; int off[15]; int n[15]; };

__global__ __launch_bounds__(256) void cvt_tab(CvtDesc d, unsigned short* __restrict__ wtab,
                                               const int* __restrict__ flagp) {
  const int seg = blockIdx.y;
  const int i = blockIdx.x * 256 + threadIdx.x;
  if (i >= d.n[seg]) return;
  unsigned short o;
  if (*flagp) o = ((const unsigned short*)d.src[seg])[i];
  else        o = f2b(((const float*)d.src[seg])[i]);
  wtab[d.off[seg] + i] = o;
}

// Block-diagonal Wq_big / Wk_big [256,256]: big[h*32+s][h*32+d]=W[s][d].
__global__ __launch_bounds__(256) void build_big(
    const unsigned short* __restrict__ wq, const unsigned short* __restrict__ wk,
    unsigned short* __restrict__ Wqbig, unsigned short* __restrict__ Wkbig)
{
  const int idx = blockIdx.x * 256 + threadIdx.x;
  const int row = idx >> 8, col = idx & 255;
  const bool same = (row >> 5) == (col >> 5);
  const int wi = (row & 31) * 32 + (col & 31);
  Wqbig[idx] = same ? wq[wi] : (unsigned short)0;
  Wkbig[idx] = same ? wk[wi] : (unsigned short)0;
}

__global__ __launch_bounds__(256) void zero_u16(unsigned short* __restrict__ p, int n) {
  int i8 = (blockIdx.x * 256 + threadIdx.x) * 8;
  if (i8 < n) { u16x8 z = {}; *(u16x8*)&p[i8] = z; }
}

// --------------------------- LN stats --------------------------------------
__global__ __launch_bounds__(256) void ln_stats(
    const void* __restrict__ X, const int* __restrict__ flagp, int amode,
    float* __restrict__ MU, float* __restrict__ RS)
{
  const int lane = threadIdx.x & 63;
  const int wave = threadIdx.x >> 6;
  const size_t row = (size_t)blockIdx.x * 4 + wave;
  const size_t base = row * 256 + lane * 4;
  const bool abf = amode ? ((*flagp) != 0) : true;
  float x0, x1, x2, x3;
  if (abf) {
    u16x4 uv = *(const u16x4*)&((const unsigned short*)X)[base];
    x0 = b2f(uv[0]); x1 = b2f(uv[1]); x2 = b2f(uv[2]); x3 = b2f(uv[3]);
  } else {
    f32x4 t = *(const f32x4*)&((const float*)X)[base];
    x0 = t[0]; x1 = t[1]; x2 = t[2]; x3 = t[3];
  }
  float s = x0 + x1 + x2 + x3;
  float q = x0*x0 + x1*x1 + x2*x2 + x3*x3;
  #pragma unroll
  for (int m = 1; m < 64; m <<= 1) { s += __shfl_xor(s, m, 64); q += __shfl_xor(q, m, 64); }
  float mean = s * (1.0f / 256.0f);
  float var  = q * (1.0f / 256.0f) - mean * mean;
  if (lane == 0) { MU[row] = mean; RS[row] = rsqrtf(var + 1e-5f); }
}

// --------------------------- generic MFMA GEMM (pipelined) ------------------
// Y[.,N] = A @ W^T + bias (+Res dtype-branched) ; act: 0 none, 2 exp,
// 3 segment-softmax (32-col segments, fused jax.nn.softmax over slices).
// 128x128 tile; 3-slot LDS ring, stage t+2 while computing t, counted vmcnt.
// z-batch: rows += z*mz, W += z*wz.
__global__ __launch_bounds__(256) void gemm_bt(
    const unsigned short* __restrict__ A,
    const unsigned short* __restrict__ W,
    const unsigned short* __restrict__ bias,
    const void* __restrict__ Res, const int* __restrict__ flagp,
    unsigned short* __restrict__ Y,
    int N, int K, int act, int mz, long wz)
{
  __shared__ __align__(16) unsigned short smem[3 * 8192];   // 48 KB ring
  const int tid = threadIdx.x, lane = tid & 63, wave = tid >> 6;
  const size_t zrow = (size_t)blockIdx.z * mz;
  const int bm = blockIdx.x * 128, bn = blockIdx.y * 128;
  const int wm = (wave >> 1) * 64, wn = (wave & 1) * 64;
  const int quad = lane >> 4, l16 = lane & 15;
  const unsigned short* Wz = W + (size_t)blockIdx.z * wz;

  f32x4 acc[4][4] = {};
  const int r0 = tid >> 2;
  const int co = (tid & 3) * 8;
  const unsigned short* pa0 = &A[(zrow + bm + r0) * K + co];
  const unsigned short* pa1 = &A[(zrow + bm + r0 + 64) * K + co];
  const unsigned short* pb0 = &Wz[(size_t)(bn + r0) * K + co];
  const unsigned short* pb1 = &Wz[(size_t)(bn + r0 + 64) * K + co];
  const int nt = K >> 5;

  auto stage = [&](int t, int sl) {
    const int k0 = t << 5;
    unsigned short* b_ = &smem[sl * 8192 + tid * 8];
    gl_lds16(pa0 + k0, b_);
    gl_lds16(pa1 + k0, b_ + 2048);
    gl_lds16(pb0 + k0, b_ + 4096);
    gl_lds16(pb1 + k0, b_ + 6144);
  };

  stage(0, 0);
  if (nt > 1) stage(1, 1);
  int scur = 0, snew = 2;
  for (int t = 0; t < nt; ++t) {
    if (t + 2 < nt) {
      stage(t + 2, snew);
      asm volatile("s_waitcnt vmcnt(8)" ::: "memory");   // tile t landed (mine)
    } else if (t + 1 < nt) {
      asm volatile("s_waitcnt vmcnt(4)" ::: "memory");
    } else {
      asm volatile("s_waitcnt vmcnt(0)" ::: "memory");
    }
    __builtin_amdgcn_s_barrier();                        // tile t landed (all)
    __builtin_amdgcn_sched_barrier(0);

    const unsigned short* sa = &smem[scur * 8192];
    const unsigned short* sb = sa + 4096;
    bf8 af[4], bfr[4];
    #pragma unroll
    for (int i = 0; i < 4; i++) af[i]  = *(const bf8*)&sa[(wm + i * 16 + l16) * 32 + quad * 8];
    #pragma unroll
    for (int j = 0; j < 4; j++) bfr[j] = *(const bf8*)&sb[(wn + j * 16 + l16) * 32 + quad * 8];
    #pragma unroll
    for (int i = 0; i < 4; i++)
      #pragma unroll
      for (int j = 0; j < 4; j++)
        acc[i][j] = __builtin_amdgcn_mfma_f32_16x16x32_bf16(af[i], bfr[j], acc[i][j], 0, 0, 0);

    __builtin_amdgcn_sched_barrier(0);
    __builtin_amdgcn_s_barrier();                        // all waves done reading slot
    scur = scur + 1 < 3 ? scur + 1 : 0;
    snew = snew + 1 < 3 ? snew + 1 : 0;
  }

  // ---- epilogue: bias/act in registers, f32 tile via LDS, coalesced stores
  const bool rbf = Res ? ((*flagp) != 0) : true;
  float bv[4];
  #pragma unroll
  for (int j = 0; j < 4; j++) bv[j] = b2f(bias[bn + wn + j * 16 + l16]);
  #pragma unroll
  for (int i = 0; i < 4; i++)
    #pragma unroll
    for (int j = 0; j < 4; j++)
      #pragma unroll
      for (int r = 0; r < 4; r++) {
        float v = acc[i][j][r] + bv[j];
        if (act == 2) v = __expf(v);
        acc[i][j][r] = v;
      }
  if (act == 3) {
    #pragma unroll
    for (int i = 0; i < 4; i++)
      #pragma unroll
      for (int g = 0; g < 2; g++)
        #pragma unroll
        for (int r = 0; r < 4; r++) {
          float a0 = acc[i][2*g][r], a1 = acc[i][2*g+1][r];
          float m = fmaxf(a0, a1);
          #pragma unroll
          for (int msk = 1; msk < 16; msk <<= 1) m = fmaxf(m, __shfl_xor(m, msk, 64));
          float e0 = __expf(a0 - m), e1 = __expf(a1 - m);
          float s = e0 + e1;
          #pragma unroll
          for (int msk = 1; msk < 16; msk <<= 1) s += __shfl_xor(s, msk, 64);
          const float rz = 1.0f / s;
          acc[i][2*g][r] = e0 * rz; acc[i][2*g+1][r] = e1 * rz;
        }
  }

  float* cf = (float*)smem;              // 64x132 f32 half-tile (33.8 KB)
  const int whalf = wm >> 6;
  #pragma unroll
  for (int half = 0; half < 2; ++half) {
    __builtin_amdgcn_s_barrier();
    if (whalf == half) {
      #pragma unroll
      for (int i = 0; i < 4; i++)
        #pragma unroll
        for (int j = 0; j < 4; j++)
          #pragma unroll
          for (int r = 0; r < 4; r++)
            cf[(i * 16 + quad * 4 + r) * 132 + wn + j * 16 + l16] = acc[i][j][r];
    }
    __builtin_amdgcn_s_barrier();
    #pragma unroll
    for (int st = 0; st < 4; ++st) {
      const int e = st * 2048 + tid * 8;
      const int row = e >> 7;
      const int col = e & 127;
      const size_t gbase = (zrow + bm + half * 64 + row) * (size_t)N + bn + col;
      float v[8];
      #pragma unroll
      for (int u = 0; u < 8; u++) v[u] = cf[row * 132 + col + u];
      if (Res) {
        if (rbf) {
          u16x8 rv = *(const u16x8*)&((const unsigned short*)Res)[gbase];
          #pragma unroll
          for (int u = 0; u < 8; u++) v[u] += b2f(rv[u]);
        } else {
          f32x4 ra = *(const f32x4*)&((const float*)Res)[gbase];
          f32x4 rb = *(const f32x4*)&((const float*)Res)[gbase + 4];
          v[0] += ra[0]; v[1] += ra[1]; v[2] += ra[2]; v[3] += ra[3];
          v[4] += rb[0]; v[5] += rb[1]; v[6] += rb[2]; v[7] += rb[3];
        }
      }
      u16x8 o;
      #pragma unroll
      for (int u = 0; u < 8; u++) o[u] = f2b(v[u]);
      *(u16x8*)&Y[gbase] = o;
    }
  }
}

// GEMM with LN applied to A during staging (amode: 1=flag dtype, 0=bf16);
// B side uses DMA staging. act=1 -> GELU. Coalesced LDS epilogue.
__global__ __launch_bounds__(256) void gemm_bt_ln(
    const void* __restrict__ A, const int* __restrict__ flagp, int amode,
    const float* __restrict__ MU, const float* __restrict__ RS,
    const unsigned short* __restrict__ lw, const unsigned short* __restrict__ lb,
    const unsigned short* __restrict__ W, const unsigned short* __restrict__ bias,
    unsigned short* __restrict__ Y, int N, int K, int act)
{
  __shared__ __align__(16) unsigned char smemc[32768];       // lA+lB, cf overlay
  unsigned short* lA = (unsigned short*)smemc;
  unsigned short* lB = lA + 4096;
  const int tid = threadIdx.x, lane = tid & 63, wave = tid >> 6;
  const int bm = blockIdx.x * 128, bn = blockIdx.y * 128;
  const int wm = (wave >> 1) * 64, wn = (wave & 1) * 64;
  const int quad = lane >> 4, l16 = lane & 15;
  const bool abf = amode ? ((*flagp) != 0) : true;
  const unsigned short* Ab = (const unsigned short*)A;
  const float* Af = (const float*)A;

  f32x4 acc[4][4] = {};
  const int r0 = tid >> 2;
  const int co = (tid & 3) * 8;
  const unsigned short* pb0 = &W[(size_t)(bn + r0) * K + co];
  const unsigned short* pb1 = &W[(size_t)(bn + r0 + 64) * K + co];

  for (int k0 = 0; k0 < K; k0 += 32) {
    u16x8 wv8 = *(const u16x8*)&lw[k0 + co];
    u16x8 bv8 = *(const u16x8*)&lb[k0 + co];
    __syncthreads();
    gl_lds16(pb0 + k0, &lB[tid * 8]);
    gl_lds16(pb1 + k0, &lB[2048 + tid * 8]);
    #pragma unroll
    for (int half = 0; half < 2; half++) {
      const int ar = bm + r0 + half * 64;
      const float m_ = MU[ar], r_ = RS[ar];
      float xv[8];
      if (abf) {
        u16x8 t = *(const u16x8*)&Ab[(size_t)ar * K + k0 + co];
        #pragma unroll
        for (int e = 0; e < 8; e++) xv[e] = b2f(t[e]);
      } else {
        f32x4 t0 = *(const f32x4*)&Af[(size_t)ar * K + k0 + co];
        f32x4 t1 = *(const f32x4*)&Af[(size_t)ar * K + k0 + co + 4];
        xv[0]=t0[0]; xv[1]=t0[1]; xv[2]=t0[2]; xv[3]=t0[3];
        xv[4]=t1[0]; xv[5]=t1[1]; xv[6]=t1[2]; xv[7]=t1[3];
      }
      u16x8 o;
      #pragma unroll
      for (int e = 0; e < 8; e++)
        o[e] = f2b((xv[e] - m_) * r_ * b2f(wv8[e]) + b2f(bv8[e]));
      *(u16x8*)&lA[half * 2048 + tid * 8] = o;
    }
    __syncthreads();

    bf8 af[4], bfr[4];
    #pragma unroll
    for (int i = 0; i < 4; i++) af[i]  = *(const bf8*)&lA[(wm + i * 16 + l16) * 32 + quad * 8];
    #pragma unroll
    for (int j = 0; j < 4; j++) bfr[j] = *(const bf8*)&lB[(wn + j * 16 + l16) * 32 + quad * 8];
    #pragma unroll
    for (int i = 0; i < 4; i++)
      #pragma unroll
      for (int j = 0; j < 4; j++)
        acc[i][j] = __builtin_amdgcn_mfma_f32_16x16x32_bf16(af[i], bfr[j], acc[i][j], 0, 0, 0);
  }

  // epilogue: bias + act in registers, coalesced store via LDS f32 tile
  float bv[4];
  #pragma unroll
  for (int j = 0; j < 4; j++) bv[j] = b2f(bias[bn + wn + j * 16 + l16]);
  #pragma unroll
  for (int i = 0; i < 4; i++)
    #pragma unroll
    for (int j = 0; j < 4; j++)
      #pragma unroll
      for (int r = 0; r < 4; r++) {
        float v = acc[i][j][r] + bv[j];
        if (act) v = gelu_exact(v);
        acc[i][j][r] = v;
      }

  float* cf = (float*)smemc;
  const int whalf = wm >> 6;
  #pragma unroll
  for (int half = 0; half < 2; ++half) {
    __syncthreads();
    if (whalf == half) {
      #pragma unroll
      for (int i = 0; i < 4; i++)
        #pragma unroll
        for (int j = 0; j < 4; j++)
          #pragma unroll
          for (int r = 0; r < 4; r++)
            cf[(i * 16 + quad * 4 + r) * 128 + wn + j * 16 + l16] = acc[i][j][r];
    }
    __syncthreads();
    #pragma unroll
    for (int st = 0; st < 4; ++st) {
      const int e = st * 2048 + tid * 8;
      const int row = e >> 7;
      const size_t gbase = (size_t)(bm + half * 64 + row) * N + bn + (e & 127);
      u16x8 o;
      #pragma unroll
      for (int u = 0; u < 8; u++) o[u] = f2b(cf[e + u]);
      *(u16x8*)&Y[gbase] = o;
    }
  }
}

// ---------------------------------------------------------------------------
// fused_mlp (R11 v3 body + parity gate): per 128-row block,
// y = GELU(LN2(h)@W1^T+b1)@W2^T + b2 + h.
// Wave w owns rows [w*32, w*32+32) (2 rg of 16); acc[2][16] f32x4;
// areg[2][8] (LN'd h in regs). Per chunk c: GEMM1 tT = W1c @ lnA^T ->
// GELU -> per-wave t tile (intra-wave) -> GEMM2 acc += t @ W2c^T.
// W1c/W2c dbuf, staged c+1 at loop top; ONE barrier/chunk.
// LDS: W1 dbuf 32K | W2 dbuf 32K | t 4x2560 @65536 | b1 @75776 = 77824 B.
// Single 512-block launch: even bid -> rows [bid/2*128 ..) (<32768, reads
// live xup, stores land in dead xm bytes); odd bid -> rows 32768+bid/2*128
// (reads ws copy, stores clobber xup bytes -> gated on all 256 low blocks
// having signalled). 2 blocks/CU => all 512 co-resident => gate can't hang.
// ---------------------------------------------------------------------------
__global__ __launch_bounds__(256, 2) void fused_mlp(
    const unsigned short* __restrict__ Hlo,
    const unsigned short* __restrict__ Hhi,
    const float* __restrict__ MU, const float* __restrict__ RS,
    const unsigned short* __restrict__ lw, const unsigned short* __restrict__ lb,
    const unsigned short* __restrict__ W1, const unsigned short* __restrict__ bs1,
    const unsigned short* __restrict__ W2, const unsigned short* __restrict__ bs2,
    void* __restrict__ OUT, const int* __restrict__ flagp,
    unsigned* __restrict__ gate)
{
  __shared__ __align__(16) unsigned char smem[77824];
  const int tid = threadIdx.x, lane = tid & 63, wave = tid >> 6;
  const int quad = lane >> 4, l16 = lane & 15;
  const int bid = blockIdx.x;
  const bool low = (bid & 1) == 0;
  const long grow = (low ? 0L : 32768L) + (long)(bid >> 1) * 128;
  const unsigned short* hbase = low ? (Hlo + (size_t)grow * 256)
                                    : (Hhi + ((size_t)grow - 32768) * 256);

  auto stageW1 = [&](int c, int b) {
    const unsigned short* src = W1 + (size_t)c * 8192;   // 32 hid-rows x 256
    unsigned char* dst = smem + b * 16384;
    #pragma unroll
    for (int s = 0; s < 4; s++) {
      const int unit = s * 256 + tid;
      const int row = unit >> 5, u = unit & 31;
      gl_lds16(src + row * 256 + ((u ^ (row & 7)) * 8), dst + unit * 16);
    }
  };
  auto stageW2 = [&](int c, int b) {
    const unsigned short* src = W2 + c * 32;             // 256 rows x 32 (of 1024)
    unsigned char* dst = smem + 32768 + b * 16384;
    #pragma unroll
    for (int s = 0; s < 4; s++) {
      const int unit = s * 256 + tid;
      const int row = unit >> 2, u = unit & 3;
      gl_lds16(src + (size_t)row * 1024 + ((u ^ ((row >> 1) & 3)) * 8), dst + unit * 16);
    }
  };

  stageW1(0, 0);
  stageW2(0, 0);

  // b1 -> LDS once (2 KB)
  unsigned short* b1l = (unsigned short*)(smem + 75776);
  if (tid < 128) *(u16x8*)&b1l[tid * 8] = *(const u16x8*)&bs1[tid * 8];

  // ---- LN2(h) A-fragments in registers, 2 row-groups:
  bf8 areg[2][8];
  #pragma unroll
  for (int rg = 0; rg < 2; rg++) {
    const int myrow = wave * 32 + rg * 16 + l16;
    const float m_ = MU[grow + myrow], r_ = RS[grow + myrow];
    const unsigned short* hr = hbase + (size_t)myrow * 256 + quad * 8;
    #pragma unroll
    for (int ks = 0; ks < 8; ks++) {
      u16x8 hv = *(const u16x8*)&hr[ks * 32];
      u16x8 wv = *(const u16x8*)&lw[ks * 32 + quad * 8];
      u16x8 bv = *(const u16x8*)&lb[ks * 32 + quad * 8];
      u16x8 o;
      #pragma unroll
      for (int e = 0; e < 8; e++)
        o[e] = f2b((b2f(hv[e]) - m_) * r_ * b2f(wv[e]) + b2f(bv[e]));
      *(u16x8*)&areg[rg][ks] = o;
    }
  }

  asm volatile("s_waitcnt vmcnt(0) lgkmcnt(0)" ::: "memory");  // chunk-0 W + b1l ready (mine)
  __builtin_amdgcn_s_barrier();                                // (all)
  __builtin_amdgcn_sched_barrier(0);

  f32x4 acc[2][16] = {};
  unsigned short* tw = (unsigned short*)(smem + 65536 + wave * 2560);
  const int gsw = (l16 >> 1) & 3;                    // W2 read swizzle
  int bsel = 0;

  for (int c = 0; c < 32; ++c) {
    if (c + 1 < 32) {
      stageW1(c + 1, bsel ^ 1);
      stageW2(c + 1, bsel ^ 1);
      __builtin_amdgcn_sched_barrier(0);
    }

    // ---- GEMM1: tT[32 hid x 32 tok] = W1c @ lnA^T
    const unsigned short* w1b = (const unsigned short*)(smem + bsel * 16384);
    f32x4 p00 = {}, p01 = {}, p10 = {}, p11 = {};
    #pragma unroll
    for (int ks = 0; ks < 8; ks++) {
      const int slot = (ks * 4 + quad) ^ (l16 & 7);
      bf8 a0, a1;
      *(u16x8*)&a0 = *(const u16x8*)&w1b[l16 * 256 + slot * 8];
      *(u16x8*)&a1 = *(const u16x8*)&w1b[(16 + l16) * 256 + slot * 8];
      p00 = __builtin_amdgcn_mfma_f32_16x16x32_bf16(a0, areg[0][ks], p00, 0, 0, 0);
      p01 = __builtin_amdgcn_mfma_f32_16x16x32_bf16(a0, areg[1][ks], p01, 0, 0, 0);
      p10 = __builtin_amdgcn_mfma_f32_16x16x32_bf16(a1, areg[0][ks], p10, 0, 0, 0);
      p11 = __builtin_amdgcn_mfma_f32_16x16x32_bf16(a1, areg[1][ks], p11, 0, 0, 0);
    }

    // ---- bias + GELU in regs; t[tok][hid] stride 40 u16 (80 B).
    {
      u16x4 bv0 = *(const u16x4*)&b1l[c * 32 + quad * 4];
      u16x4 bv1 = *(const u16x4*)&b1l[c * 32 + 16 + quad * 4];
      u16x4 o00, o01, o10, o11;
      #pragma unroll
      for (int r = 0; r < 4; r++) {
        o00[r] = f2b(gelu_fast(p00[r] + b2f(bv0[r])));
        o01[r] = f2b(gelu_fast(p01[r] + b2f(bv0[r])));
        o10[r] = f2b(gelu_fast(p10[r] + b2f(bv1[r])));
        o11[r] = f2b(gelu_fast(p11[r] + b2f(bv1[r])));
      }
      *(u16x4*)&tw[l16 * 40 + quad * 4]             = o00;   // rg0, hid 0-15
      *(u16x4*)&tw[(16 + l16) * 40 + quad * 4]      = o01;   // rg1, hid 0-15
      *(u16x4*)&tw[l16 * 40 + 16 + quad * 4]        = o10;   // rg0, hid 16-31
      *(u16x4*)&tw[(16 + l16) * 40 + 16 + quad * 4] = o11;   // rg1, hid 16-31
    }
    asm volatile("s_waitcnt lgkmcnt(0)" ::: "memory");   // t visible (intra-wave)
    __builtin_amdgcn_sched_barrier(0);

    // ---- GEMM2: acc[rg][j] += t @ W2c^T
    bf8 ta0, ta1;
    *(u16x8*)&ta0 = *(const u16x8*)&tw[l16 * 40 + quad * 8];
    *(u16x8*)&ta1 = *(const u16x8*)&tw[(16 + l16) * 40 + quad * 8];
    const unsigned short* w2b = (const unsigned short*)(smem + 32768 + bsel * 16384);
    #pragma unroll
    for (int j = 0; j < 16; j++) {
      bf8 bw;
      *(u16x8*)&bw = *(const u16x8*)&w2b[(j * 16 + l16) * 32 + ((quad ^ gsw) * 8)];
      acc[0][j] = __builtin_amdgcn_mfma_f32_16x16x32_bf16(ta0, bw, acc[0][j], 0, 0, 0);
      acc[1][j] = __builtin_amdgcn_mfma_f32_16x16x32_bf16(ta1, bw, acc[1][j], 0, 0, 0);
    }

    asm volatile("s_waitcnt vmcnt(0)" ::: "memory");   // my c+1 staging landed
    __builtin_amdgcn_s_barrier();                      // all reads of bsel done, c+1 ready
    __builtin_amdgcn_sched_barrier(0);
    bsel ^= 1;
  }

  // ---- gate: high blocks must not write xup bytes until all low blocks
  //      have finished reading h (their final __syncthreads drained vmcnt).
  if (!low) {
    if (tid == 0) {
      while (__hip_atomic_load(gate, __ATOMIC_ACQUIRE, __HIP_MEMORY_SCOPE_AGENT) < 256u)
        __builtin_amdgcn_s_sleep(32);
    }
    __syncthreads();
  }

  // ---- epilogue: two 64-row halves through cf [64][260] f32 (overlays W/t)
  const bool obf = (*flagp) != 0;
  float* cf = (float*)smem;
  #pragma unroll
  for (int hh = 0; hh < 2; ++hh) {
    __syncthreads();
    if ((wave >> 1) == hh) {
      const int wl = (wave & 1) * 32;
      #pragma unroll
      for (int rg = 0; rg < 2; rg++)
        #pragma unroll
        for (int j = 0; j < 16; j++)
          #pragma unroll
          for (int r = 0; r < 4; r++)
            cf[(wl + rg * 16 + quad * 4 + r) * 260 + j * 16 + l16] = acc[rg][j][r];
    }
    __syncthreads();
    const unsigned short* hrow = hbase + (size_t)(hh * 64) * 256;
    #pragma unroll
    for (int s = 0; s < 8; s++) {
      const int e = s * 2048 + tid * 8;
      const int row = e >> 8, col = e & 255;
      u16x8 rv = *(const u16x8*)&hrow[e];
      u16x8 b2v = *(const u16x8*)&bs2[col];
      float v[8];
      #pragma unroll
      for (int u = 0; u < 8; u++) v[u] = cf[row * 260 + col + u] + b2f(rv[u]) + b2f(b2v[u]);
      const size_t ob = (size_t)(grow + hh * 64 + row) * 256 + col;
      if (obf) {
        u16x8 o;
        #pragma unroll
        for (int u = 0; u < 8; u++) o[u] = f2b(v[u]);
        *(u16x8*)&((unsigned short*)OUT)[ob] = o;
      } else {
        f32x4 oa, obv;
        oa[0]=v[0]; oa[1]=v[1]; oa[2]=v[2]; oa[3]=v[3];
        obv[0]=v[4]; obv[1]=v[5]; obv[2]=v[6]; obv[3]=v[7];
        *(f32x4*)&((float*)OUT)[ob] = oa;
        *(f32x4*)&((float*)OUT)[ob + 4] = obv;
      }
    }
  }

  // ---- low blocks signal: all their h reads are complete (the barrier
  //      above each wave's arrival drained its vmcnt).
  if (low) {
    __syncthreads();
    if (tid == 0)
      __hip_atomic_fetch_add(gate, 1u, __ATOMIC_RELEASE, __HIP_MEMORY_SCOPE_AGENT);
  }
}

// ---------------------------------------------------------------------------
// accumG: per 256-token block k: partial G[h,s,d] = sum_n E[n,h*32+s]*X[n,h*32+d]
// (+ z partial at [8192+tid]). Batch b owns blocks k = b*32 .. b*32+31.
// ---------------------------------------------------------------------------
__global__ __launch_bounds__(256) void accumG(
    const unsigned short* __restrict__ X,
    const unsigned short* __restrict__ E,
    float* __restrict__ Gp)                 // [256][8448]
{
  __shared__ float Xl[64 * 256];                         // 64 KB
  __shared__ __align__(16) unsigned short El[64 * 256];  // 32 KB
  const int tid = threadIdx.x;
  const int k = blockIdx.x;
  const int h = tid >> 5, s = tid & 31;

  float acc[32];
  #pragma unroll
  for (int d = 0; d < 32; d++) acc[d] = 0.f;
  float zacc = 0.f;

  for (int sub = 0; sub < 4; sub++) {
    const size_t r0s = (size_t)k * 256 + sub * 64;
    __syncthreads();
    #pragma unroll
    for (int i = 0; i < 8; i++) {
      const int flat = i * 2048 + tid * 8;
      u16x8 xv = *(const u16x8*)&X[r0s * 256 + flat];
      #pragma unroll
      for (int e = 0; e < 8; e++) Xl[flat + e] = b2f(xv[e]);
      *(u16x8*)&El[flat] = *(const u16x8*)&E[r0s * 256 + flat];
    }
    __syncthreads();

    for (int t = 0; t < 64; t++) {
      const float e = b2f(El[t * 256 + h * 32 + s]);
      zacc += e;
      const int xb = t * 256 + h * 32;
      #pragma unroll
      for (int dq = 0; dq < 8; dq++) {
        f32x4 xv = *(const f32x4*)&Xl[xb + dq * 4];
        acc[dq*4+0] += e * xv[0];
        acc[dq*4+1] += e * xv[1];
        acc[dq*4+2] += e * xv[2];
        acc[dq*4+3] += e * xv[3];
      }
    }
  }

  float* gp = &Gp[(size_t)k * 8448 + (size_t)tid * 32];
  #pragma unroll
  for (int dq = 0; dq < 8; dq++) {
    f32x4 o; o[0]=acc[dq*4]; o[1]=acc[dq*4+1]; o[2]=acc[dq*4+2]; o[3]=acc[dq*4+3];
    *(f32x4*)&gp[dq * 4] = o;
  }
  Gp[(size_t)k * 8448 + 8192 + tid] = zacc;
}

// Gfin[b][j] = sum_{i<32} Gp[b*32+i][j], b in 0..7.
__global__ __launch_bounds__(256) void reduceG(const float* __restrict__ Gp,
                                               float* __restrict__ Gfin) {
  const int o = blockIdx.x * 256 + threadIdx.x;
  if (o >= 67584) return;
  const int b = o / 8448;
  const int j = o - b * 8448;
  float s = 0.f;
  #pragma unroll 8
  for (int i = 0; i < 32; i++) s += Gp[(size_t)(b * 32 + i) * 8448 + j];
  Gfin[o] = s;
}

// kv_build (8 blocks): kv[b,h,s,d] = (sum_dd G*Wv[d,dd]) / z; block-diag KVB.
__global__ __launch_bounds__(256) void kv_build(
    const float* __restrict__ Gfin, const unsigned short* __restrict__ Wv,
    unsigned short* __restrict__ KVB)
{
  __shared__ float Gl[8192];
  __shared__ float zl[256];
  __shared__ float wvt[1024];
  const int tid = threadIdx.x;
  const int b = blockIdx.x;
  for (int i = tid; i < 8192; i += 256) Gl[i] = Gfin[(size_t)b * 8448 + i];
  zl[tid] = Gfin[(size_t)b * 8448 + 8192 + tid];
  for (int i = tid; i < 1024; i += 256) {
    const int dd = i >> 5, d = i & 31;
    wvt[i] = b2f(Wv[d * 32 + dd]);
  }
  __syncthreads();

  const int h = tid >> 5, d = tid & 31;
  unsigned short row[32];
  for (int s = 0; s < 32; s++) {
    float a = 0.f;
    #pragma unroll
    for (int dd = 0; dd < 32; dd++) a += Gl[h * 1024 + s * 32 + dd] * wvt[dd * 32 + d];
    row[s] = f2b(a / zl[h * 32 + s]);
  }
  unsigned short* out = &KVB[(size_t)b * 65536 + (size_t)(h * 32 + d) * 256 + h * 32];
  #pragma unroll
  for (int e = 0; e < 4; e++) *(u16x8*)&out[e * 8] = *(u16x8*)&row[e * 8];
}

__global__ __launch_bounds__(256) void copy_h0(const unsigned short* __restrict__ src,
                                               unsigned short* __restrict__ dst) {
  size_t i = ((size_t)blockIdx.x * 256 + threadIdx.x) * 8;
  *(u16x8*)&dst[i] = *(const u16x8*)&src[i];
}

// ---------------------------------------------------------------------------
extern "C" void kernel_launch(void* const* d_in, const int* in_sizes, int n_in,
                              void* d_out, int out_size, void* d_ws, size_t ws_size,
                              hipStream_t stream)
{
  const void* fx   = d_in[0];
  const void* ln1w = d_in[1];
  const void* ln1b = d_in[2];
  const void* Wx   = d_in[3];
  const void* bx   = d_in[4];
  const void* Wq   = d_in[5];
  const void* Wk   = d_in[6];
  const void* Wv   = d_in[7];
  const void* Wo   = d_in[8];
  const void* bo   = d_in[9];
  const void* ln2w = d_in[10];
  const void* ln2b = d_in[11];
  const void* W1   = d_in[12];
  const void* b1   = d_in[13];
  const void* W2   = d_in[14];
  const void* b2   = d_in[15];

  // ws layout (~24.7 MB)
  unsigned short* ws    = (unsigned short*)d_ws;
  unsigned short* hid   = ws;                      // 8,388,608 u16 (16 MB): h-upper copy
  float* Gp             = (float*)ws;              // overlay: 256*8448 f32 (dead by MLP)
  unsigned short* wtab  = ws + 8388608;            // 661,248 u16
  unsigned short* h0res = wtab + 661248;           // 2,097,152 u16 (4 MB)
  float* Gfin           = (float*)h0res;           // overlay: 67,584 f32
  unsigned short* Wqbig = h0res + 2097152;         // 65,536
  unsigned short* Wkbig = Wqbig + 65536;           // 65,536
  unsigned short* KVB   = Wkbig + 65536;           // 524,288
  unsigned short* zbias = KVB + 524288;            // 256
  float* fpw = (float*)(zbias + 256);
  float* mu1 = fpw;
  float* rs1 = fpw + 65536;
  float* mu2 = fpw + 131072;
  float* rs2 = fpw + 196608;
  int* flagp = (int*)(fpw + 262144);
  unsigned* gatep = (unsigned*)(flagp + 1);

  const int OFF_LN1W=0, OFF_LN1B=256, OFF_WX=512, OFF_BX=66048,
            OFF_WQ=66304, OFF_WK=67328, OFF_WV=68352,
            OFF_WO=69376, OFF_BO=134912, OFF_LN2W=135168, OFF_LN2B=135424,
            OFF_W1=135680, OFF_B1=397824, OFF_W2=398848, OFF_B2=660992;

  unsigned short* xm  = (unsigned short*)d_out;    // lower: xmid->qkv2d (dead after Wo)
  unsigned short* xup = xm + 16777216;             // upper: E2d->QL->Qs->h

  // 0. dtype sniff + gate zero + weight table
  sniff_kernel<<<1, 64, 0, stream>>>((const unsigned*)fx, flagp, gatep);
  CvtDesc cd;
  const void* srcs[15] = {ln1w, ln1b, Wx, bx, Wq, Wk, Wv, Wo, bo, ln2w, ln2b, W1, b1, W2, b2};
  const int offs[15]   = {OFF_LN1W, OFF_LN1B, OFF_WX, OFF_BX, OFF_WQ, OFF_WK, OFF_WV,
                          OFF_WO, OFF_BO, OFF_LN2W, OFF_LN2B, OFF_W1, OFF_B1, OFF_W2, OFF_B2};
  const int ns[15]     = {256, 256, 65536, 256, 1024, 1024, 1024, 65536, 256, 256, 256,
                          262144, 1024, 262144, 256};
  for (int i = 0; i < 15; i++) { cd.src[i] = srcs[i]; cd.off[i] = offs[i]; cd.n[i] = ns[i]; }
  cvt_tab<<<dim3(1024, 15), 256, 0, stream>>>(cd, wtab, flagp);
  build_big<<<256, 256, 0, stream>>>(wtab + OFF_WQ, wtab + OFF_WK, Wqbig, Wkbig);
  zero_u16<<<257, 256, 0, stream>>>(KVB, 524544);

  // 1. LN1 stats; xmid = LN1(fx) @ Wx^T + bx -> xm
  ln_stats<<<16384, 256, 0, stream>>>(fx, flagp, 1, mu1, rs1);
  gemm_bt_ln<<<dim3(512, 2), 256, 0, stream>>>(fx, flagp, 1, mu1, rs1,
      wtab + OFF_LN1W, wtab + OFF_LN1B, wtab + OFF_WX, wtab + OFF_BX,
      xm, 256, 256, 0);

  // 2. E2d = exp(xmid @ Wkbig^T) -> xup
  gemm_bt<<<dim3(512, 2), 256, 0, stream>>>(xm, Wkbig, zbias, nullptr, flagp,
                                            xup, 256, 256, 2, 0, 0);

  // 3. G partials + reduce; kv -> KVB block-diag
  accumG<<<256, 256, 0, stream>>>(xm, xup, Gp);
  reduceG<<<264, 256, 0, stream>>>(Gp, Gfin);
  kv_build<<<8, 256, 0, stream>>>(Gfin, wtab + OFF_WV, KVB);

  // 4. Qs = segsoftmax(xmid @ Wqbig^T) -> xup (E2d dead), fused in epilogue
  gemm_bt<<<dim3(512, 2), 256, 0, stream>>>(xm, Wqbig, zbias, nullptr, flagp,
                                            xup, 256, 256, 3, 0, 0);

  // 5. qkv2d = Qs @ KVB[b]^T -> xm (xmid dead), z-batched over b
  gemm_bt<<<dim3(64, 2, 8), 256, 0, stream>>>(xup, KVB, zbias, nullptr, flagp,
                                              xm, 256, 256, 0, 8192, 65536);

  // 6. h = qkv2d @ Wo^T + bo + fx -> xup (Qs dead; NOT in-place -> full grid)
  gemm_bt<<<dim3(512, 2), 256, 0, stream>>>(xm, wtab + OFF_WO, wtab + OFF_BO, fx, flagp,
                                            xup, 256, 256, 0, 0, 0);

  // 7. LN2 stats on h; copy h rows [32768,65536) -> ws hid area (Gp dead).
  ln_stats<<<16384, 256, 0, stream>>>(xup, flagp, 0, mu2, rs2);
  copy_h0<<<4096, 256, 0, stream>>>(xup + (size_t)32768 * 256, hid);

  // 8. fused MLP: y = GELU(LN2(h)@W1^T+b1)@W2^T + b2 + h
  //    single 512-block launch (2 blocks/CU); even bid = low rows (live h,
  //    dead-byte stores), odd bid = high rows (copy h, gated stores).
  fused_mlp<<<512, 256, 0, stream>>>(xup, hid, mu2, rs2,
      wtab + OFF_LN2W, wtab + OFF_LN2B, wtab + OFF_W1, wtab + OFF_B1,
      wtab + OFF_W2, wtab + OFF_B2, d_out, flagp, gatep);
}

// Round 7
// 485.253 us; speedup vs baseline: 1.0234x; 1.0234x over previous
//
#include <hip/hip_runtime.h>
#include <math.h>

// ---------------------------------------------------------------------------
// LinearNO block, MI355X/gfx950. Inputs fp32 (sniffed; bf16 fallback).
// Interior bf16 MFMA. B=8 N=8192 C=256 H=8 D=32 S=32.
//
// R14 changes vs R13 (497 us, fused_mlp 157 us):
//  * fused_mlp v5: cross-chunk software pipeline. Per-chunk phases were a
//    serial chain ending in vmcnt(0)+barrier (the m97 stall); pipe totals
//    (MFMA 33 + LDS 54 + VALU 44 us) were running UNOVERLAPPED (141 ~= 157).
//    Now between two barriers: GEMM1(c+1) || GELU(c) || GEMM2(c) || stage.
//    GELU(c) consumes p-regs from GEMM1(c) run LAST iter -> VALU overlaps
//    MFMA/LDS. W1 3-slot ring (staged 2 ahead), W2 2-slot (staged after the
//    barrier); mid-loop wait is vmcnt(2), NEVER 0. One barrier per chunk.
//    BM=256, 512 thr / 8 waves, LDS 104448 -> 256 blocks = 1/CU, ALL
//    co-resident -> parity gate (target 128) provably deadlock-free.
// ---------------------------------------------------------------------------

typedef __attribute__((ext_vector_type(8))) short bf8;
typedef __attribute__((ext_vector_type(4))) float f32x4;
typedef __attribute__((ext_vector_type(4))) unsigned short u16x4;
typedef __attribute__((ext_vector_type(8))) unsigned short u16x8;

__device__ __forceinline__ float b2f(unsigned short x) {
  union { unsigned u; float f; } t; t.u = ((unsigned)x) << 16; return t.f;
}
__device__ __forceinline__ unsigned short f2b(float f) {
  union { float f; unsigned u; } t; t.f = f;
  unsigned r = t.u + 0x7fffu + ((t.u >> 16) & 1u);
  return (unsigned short)(r >> 16);
}
__device__ __forceinline__ float gelu_exact(float x) {
  return 0.5f * x * (1.0f + erff(x * 0.7071067811865475f));
}
// A&S 7.1.26 erf, |eps| <= 1.5e-7 (abs). Much cheaper than libm erff.
__device__ __forceinline__ float erf_fast(float x) {
  float ax = fabsf(x);
  float t = __builtin_amdgcn_rcpf(fmaf(0.3275911f, ax, 1.0f));
  float p = t * fmaf(t, fmaf(t, fmaf(t, fmaf(t, 1.061405429f, -1.453152027f),
                                     1.421413741f), -0.284496736f), 0.254829592f);
  float r = 1.0f - p * __expf(-ax * ax);
  return copysignf(r, x);
}
__device__ __forceinline__ float gelu_fast(float x) {
  return 0.5f * x * (1.0f + erf_fast(x * 0.7071067811865475f));
}

// async global->LDS, 16 B per lane. LDS dest must be base + lane*16.
typedef __attribute__((address_space(1))) const void gas_void;
typedef __attribute__((address_space(3))) void las_void;
__device__ __forceinline__ void gl_lds16(const void* g, void* l) {
  __builtin_amdgcn_global_load_lds((gas_void*)g, (las_void*)l, 16, 0, 0);
}

// --------------------------- dtype sniffer ---------------------------------
__global__ void sniff_kernel(const unsigned* __restrict__ fx, int* __restrict__ flag,
                             unsigned* __restrict__ gate) {
  if (threadIdx.x == 0) {
    int cnt = 0;
    for (int i = 0; i < 64; i++) {
      unsigned e = (fx[i] >> 7) & 0xFFu;
      cnt += (e >= 117u && e <= 130u) ? 1 : 0;
    }
    *flag = (cnt >= 32) ? 1 : 0;   // 1 = bf16 inputs, 0 = fp32
    *gate = 0u;                    // MLP ordering gate (re-zeroed every replay)
  }
}

// --------------------------- weight table ----------------------------------
struct CvtDesc { const void* src[15]; int off[15]; int n[15]; };

__global__ __launch_bounds__(256) void cvt_tab(CvtDesc d, unsigned short* __restrict__ wtab,
                                               const int* __restrict__ flagp) {
  const int seg = blockIdx.y;
  const int i = blockIdx.x * 256 + threadIdx.x;
  if (i >= d.n[seg]) return;
  unsigned short o;
  if (*flagp) o = ((const unsigned short*)d.src[seg])[i];
  else        o = f2b(((const float*)d.src[seg])[i]);
  wtab[d.off[seg] + i] = o;
}

// Block-diagonal Wq_big / Wk_big [256,256]: big[h*32+s][h*32+d]=W[s][d].
__global__ __launch_bounds__(256) void build_big(
    const unsigned short* __restrict__ wq, const unsigned short* __restrict__ wk,
    unsigned short* __restrict__ Wqbig, unsigned short* __restrict__ Wkbig)
{
  const int idx = blockIdx.x * 256 + threadIdx.x;
  const int row = idx >> 8, col = idx & 255;
  const bool same = (row >> 5) == (col >> 5);
  const int wi = (row & 31) * 32 + (col & 31);
  Wqbig[idx] = same ? wq[wi] : (unsigned short)0;
  Wkbig[idx] = same ? wk[wi] : (unsigned short)0;
}

__global__ __launch_bounds__(256) void zero_u16(unsigned short* __restrict__ p, int n) {
  int i8 = (blockIdx.x * 256 + threadIdx.x) * 8;
  if (i8 < n) { u16x8 z = {}; *(u16x8*)&p[i8] = z; }
}

// --------------------------- LN stats --------------------------------------
__global__ __launch_bounds__(256) void ln_stats(
    const void* __restrict__ X, const int* __restrict__ flagp, int amode,
    float* __restrict__ MU, float* __restrict__ RS)
{
  const int lane = threadIdx.x & 63;
  const int wave = threadIdx.x >> 6;
  const size_t row = (size_t)blockIdx.x * 4 + wave;
  const size_t base = row * 256 + lane * 4;
  const bool abf = amode ? ((*flagp) != 0) : true;
  float x0, x1, x2, x3;
  if (abf) {
    u16x4 uv = *(const u16x4*)&((const unsigned short*)X)[base];
    x0 = b2f(uv[0]); x1 = b2f(uv[1]); x2 = b2f(uv[2]); x3 = b2f(uv[3]);
  } else {
    f32x4 t = *(const f32x4*)&((const float*)X)[base];
    x0 = t[0]; x1 = t[1]; x2 = t[2]; x3 = t[3];
  }
  float s = x0 + x1 + x2 + x3;
  float q = x0*x0 + x1*x1 + x2*x2 + x3*x3;
  #pragma unroll
  for (int m = 1; m < 64; m <<= 1) { s += __shfl_xor(s, m, 64); q += __shfl_xor(q, m, 64); }
  float mean = s * (1.0f / 256.0f);
  float var  = q * (1.0f / 256.0f) - mean * mean;
  if (lane == 0) { MU[row] = mean; RS[row] = rsqrtf(var + 1e-5f); }
}

// --------------------------- generic MFMA GEMM (pipelined) ------------------
// Y[.,N] = A @ W^T + bias (+Res dtype-branched) ; act: 0 none, 2 exp,
// 3 segment-softmax (32-col segments, fused jax.nn.softmax over slices).
// 128x128 tile; 3-slot LDS ring, stage t+2 while computing t, counted vmcnt.
// z-batch: rows += z*mz, W += z*wz.
__global__ __launch_bounds__(256) void gemm_bt(
    const unsigned short* __restrict__ A,
    const unsigned short* __restrict__ W,
    const unsigned short* __restrict__ bias,
    const void* __restrict__ Res, const int* __restrict__ flagp,
    unsigned short* __restrict__ Y,
    int N, int K, int act, int mz, long wz)
{
  __shared__ __align__(16) unsigned short smem[3 * 8192];   // 48 KB ring
  const int tid = threadIdx.x, lane = tid & 63, wave = tid >> 6;
  const size_t zrow = (size_t)blockIdx.z * mz;
  const int bm = blockIdx.x * 128, bn = blockIdx.y * 128;
  const int wm = (wave >> 1) * 64, wn = (wave & 1) * 64;
  const int quad = lane >> 4, l16 = lane & 15;
  const unsigned short* Wz = W + (size_t)blockIdx.z * wz;

  f32x4 acc[4][4] = {};
  const int r0 = tid >> 2;
  const int co = (tid & 3) * 8;
  const unsigned short* pa0 = &A[(zrow + bm + r0) * K + co];
  const unsigned short* pa1 = &A[(zrow + bm + r0 + 64) * K + co];
  const unsigned short* pb0 = &Wz[(size_t)(bn + r0) * K + co];
  const unsigned short* pb1 = &Wz[(size_t)(bn + r0 + 64) * K + co];
  const int nt = K >> 5;

  auto stage = [&](int t, int sl) {
    const int k0 = t << 5;
    unsigned short* b_ = &smem[sl * 8192 + tid * 8];
    gl_lds16(pa0 + k0, b_);
    gl_lds16(pa1 + k0, b_ + 2048);
    gl_lds16(pb0 + k0, b_ + 4096);
    gl_lds16(pb1 + k0, b_ + 6144);
  };

  stage(0, 0);
  if (nt > 1) stage(1, 1);
  int scur = 0, snew = 2;
  for (int t = 0; t < nt; ++t) {
    if (t + 2 < nt) {
      stage(t + 2, snew);
      asm volatile("s_waitcnt vmcnt(8)" ::: "memory");   // tile t landed (mine)
    } else if (t + 1 < nt) {
      asm volatile("s_waitcnt vmcnt(4)" ::: "memory");
    } else {
      asm volatile("s_waitcnt vmcnt(0)" ::: "memory");
    }
    __builtin_amdgcn_s_barrier();                        // tile t landed (all)
    __builtin_amdgcn_sched_barrier(0);

    const unsigned short* sa = &smem[scur * 8192];
    const unsigned short* sb = sa + 4096;
    bf8 af[4], bfr[4];
    #pragma unroll
    for (int i = 0; i < 4; i++) af[i]  = *(const bf8*)&sa[(wm + i * 16 + l16) * 32 + quad * 8];
    #pragma unroll
    for (int j = 0; j < 4; j++) bfr[j] = *(const bf8*)&sb[(wn + j * 16 + l16) * 32 + quad * 8];
    #pragma unroll
    for (int i = 0; i < 4; i++)
      #pragma unroll
      for (int j = 0; j < 4; j++)
        acc[i][j] = __builtin_amdgcn_mfma_f32_16x16x32_bf16(af[i], bfr[j], acc[i][j], 0, 0, 0);

    __builtin_amdgcn_sched_barrier(0);
    __builtin_amdgcn_s_barrier();                        // all waves done reading slot
    scur = scur + 1 < 3 ? scur + 1 : 0;
    snew = snew + 1 < 3 ? snew + 1 : 0;
  }

  // ---- epilogue: bias/act in registers, f32 tile via LDS, coalesced stores
  const bool rbf = Res ? ((*flagp) != 0) : true;
  float bv[4];
  #pragma unroll
  for (int j = 0; j < 4; j++) bv[j] = b2f(bias[bn + wn + j * 16 + l16]);
  #pragma unroll
  for (int i = 0; i < 4; i++)
    #pragma unroll
    for (int j = 0; j < 4; j++)
      #pragma unroll
      for (int r = 0; r < 4; r++) {
        float v = acc[i][j][r] + bv[j];
        if (act == 2) v = __expf(v);
        acc[i][j][r] = v;
      }
  if (act == 3) {
    #pragma unroll
    for (int i = 0; i < 4; i++)
      #pragma unroll
      for (int g = 0; g < 2; g++)
        #pragma unroll
        for (int r = 0; r < 4; r++) {
          float a0 = acc[i][2*g][r], a1 = acc[i][2*g+1][r];
          float m = fmaxf(a0, a1);
          #pragma unroll
          for (int msk = 1; msk < 16; msk <<= 1) m = fmaxf(m, __shfl_xor(m, msk, 64));
          float e0 = __expf(a0 - m), e1 = __expf(a1 - m);
          float s = e0 + e1;
          #pragma unroll
          for (int msk = 1; msk < 16; msk <<= 1) s += __shfl_xor(s, msk, 64);
          const float rz = 1.0f / s;
          acc[i][2*g][r] = e0 * rz; acc[i][2*g+1][r] = e1 * rz;
        }
  }

  float* cf = (float*)smem;              // 64x132 f32 half-tile (33.8 KB)
  const int whalf = wm >> 6;
  #pragma unroll
  for (int half = 0; half < 2; ++half) {
    __builtin_amdgcn_s_barrier();
    if (whalf == half) {
      #pragma unroll
      for (int i = 0; i < 4; i++)
        #pragma unroll
        for (int j = 0; j < 4; j++)
          #pragma unroll
          for (int r = 0; r < 4; r++)
            cf[(i * 16 + quad * 4 + r) * 132 + wn + j * 16 + l16] = acc[i][j][r];
    }
    __builtin_amdgcn_s_barrier();
    #pragma unroll
    for (int st = 0; st < 4; ++st) {
      const int e = st * 2048 + tid * 8;
      const int row = e >> 7;
      const int col = e & 127;
      const size_t gbase = (zrow + bm + half * 64 + row) * (size_t)N + bn + col;
      float v[8];
      #pragma unroll
      for (int u = 0; u < 8; u++) v[u] = cf[row * 132 + col + u];
      if (Res) {
        if (rbf) {
          u16x8 rv = *(const u16x8*)&((const unsigned short*)Res)[gbase];
          #pragma unroll
          for (int u = 0; u < 8; u++) v[u] += b2f(rv[u]);
        } else {
          f32x4 ra = *(const f32x4*)&((const float*)Res)[gbase];
          f32x4 rb = *(const f32x4*)&((const float*)Res)[gbase + 4];
          v[0] += ra[0]; v[1] += ra[1]; v[2] += ra[2]; v[3] += ra[3];
          v[4] += rb[0]; v[5] += rb[1]; v[6] += rb[2]; v[7] += rb[3];
        }
      }
      u16x8 o;
      #pragma unroll
      for (int u = 0; u < 8; u++) o[u] = f2b(v[u]);
      *(u16x8*)&Y[gbase] = o;
    }
  }
}

// GEMM with LN applied to A during staging (amode: 1=flag dtype, 0=bf16);
// B side uses DMA staging. act=1 -> GELU. Coalesced LDS epilogue.
__global__ __launch_bounds__(256) void gemm_bt_ln(
    const void* __restrict__ A, const int* __restrict__ flagp, int amode,
    const float* __restrict__ MU, const float* __restrict__ RS,
    const unsigned short* __restrict__ lw, const unsigned short* __restrict__ lb,
    const unsigned short* __restrict__ W, const unsigned short* __restrict__ bias,
    unsigned short* __restrict__ Y, int N, int K, int act)
{
  __shared__ __align__(16) unsigned char smemc[32768];       // lA+lB, cf overlay
  unsigned short* lA = (unsigned short*)smemc;
  unsigned short* lB = lA + 4096;
  const int tid = threadIdx.x, lane = tid & 63, wave = tid >> 6;
  const int bm = blockIdx.x * 128, bn = blockIdx.y * 128;
  const int wm = (wave >> 1) * 64, wn = (wave & 1) * 64;
  const int quad = lane >> 4, l16 = lane & 15;
  const bool abf = amode ? ((*flagp) != 0) : true;
  const unsigned short* Ab = (const unsigned short*)A;
  const float* Af = (const float*)A;

  f32x4 acc[4][4] = {};
  const int r0 = tid >> 2;
  const int co = (tid & 3) * 8;
  const unsigned short* pb0 = &W[(size_t)(bn + r0) * K + co];
  const unsigned short* pb1 = &W[(size_t)(bn + r0 + 64) * K + co];

  for (int k0 = 0; k0 < K; k0 += 32) {
    u16x8 wv8 = *(const u16x8*)&lw[k0 + co];
    u16x8 bv8 = *(const u16x8*)&lb[k0 + co];
    __syncthreads();
    gl_lds16(pb0 + k0, &lB[tid * 8]);
    gl_lds16(pb1 + k0, &lB[2048 + tid * 8]);
    #pragma unroll
    for (int half = 0; half < 2; half++) {
      const int ar = bm + r0 + half * 64;
      const float m_ = MU[ar], r_ = RS[ar];
      float xv[8];
      if (abf) {
        u16x8 t = *(const u16x8*)&Ab[(size_t)ar * K + k0 + co];
        #pragma unroll
        for (int e = 0; e < 8; e++) xv[e] = b2f(t[e]);
      } else {
        f32x4 t0 = *(const f32x4*)&Af[(size_t)ar * K + k0 + co];
        f32x4 t1 = *(const f32x4*)&Af[(size_t)ar * K + k0 + co + 4];
        xv[0]=t0[0]; xv[1]=t0[1]; xv[2]=t0[2]; xv[3]=t0[3];
        xv[4]=t1[0]; xv[5]=t1[1]; xv[6]=t1[2]; xv[7]=t1[3];
      }
      u16x8 o;
      #pragma unroll
      for (int e = 0; e < 8; e++)
        o[e] = f2b((xv[e] - m_) * r_ * b2f(wv8[e]) + b2f(bv8[e]));
      *(u16x8*)&lA[half * 2048 + tid * 8] = o;
    }
    __syncthreads();

    bf8 af[4], bfr[4];
    #pragma unroll
    for (int i = 0; i < 4; i++) af[i]  = *(const bf8*)&lA[(wm + i * 16 + l16) * 32 + quad * 8];
    #pragma unroll
    for (int j = 0; j < 4; j++) bfr[j] = *(const bf8*)&lB[(wn + j * 16 + l16) * 32 + quad * 8];
    #pragma unroll
    for (int i = 0; i < 4; i++)
      #pragma unroll
      for (int j = 0; j < 4; j++)
        acc[i][j] = __builtin_amdgcn_mfma_f32_16x16x32_bf16(af[i], bfr[j], acc[i][j], 0, 0, 0);
  }

  // epilogue: bias + act in registers, coalesced store via LDS f32 tile
  float bv[4];
  #pragma unroll
  for (int j = 0; j < 4; j++) bv[j] = b2f(bias[bn + wn + j * 16 + l16]);
  #pragma unroll
  for (int i = 0; i < 4; i++)
    #pragma unroll
    for (int j = 0; j < 4; j++)
      #pragma unroll
      for (int r = 0; r < 4; r++) {
        float v = acc[i][j][r] + bv[j];
        if (act) v = gelu_exact(v);
        acc[i][j][r] = v;
      }

  float* cf = (float*)smemc;
  const int whalf = wm >> 6;
  #pragma unroll
  for (int half = 0; half < 2; ++half) {
    __syncthreads();
    if (whalf == half) {
      #pragma unroll
      for (int i = 0; i < 4; i++)
        #pragma unroll
        for (int j = 0; j < 4; j++)
          #pragma unroll
          for (int r = 0; r < 4; r++)
            cf[(i * 16 + quad * 4 + r) * 128 + wn + j * 16 + l16] = acc[i][j][r];
    }
    __syncthreads();
    #pragma unroll
    for (int st = 0; st < 4; ++st) {
      const int e = st * 2048 + tid * 8;
      const int row = e >> 7;
      const size_t gbase = (size_t)(bm + half * 64 + row) * N + bn + (e & 127);
      u16x8 o;
      #pragma unroll
      for (int u = 0; u < 8; u++) o[u] = f2b(cf[e + u]);
      *(u16x8*)&Y[gbase] = o;
    }
  }
}

// ---------------------------------------------------------------------------
// fused_mlp v5 (cross-chunk pipelined): per 256-row block,
// y = GELU(LN2(h)@W1^T+b1)@W2^T + b2 + h. 512 thr / 8 waves; wave w owns
// rows [w*32, w*32+32). Per chunk, between two barriers:
//   stageW1(c+2) | GELU(c)+twrite (p from GEMM1(c), prev iter) |
//   tread+GEMM2(c) | vmcnt(2) barrier | stageW2(c+2) + GEMM1(c+1)
// W1 3-slot ring @0 (48K), W2 2-slot @49152 (32K), t 8x2560 @81920,
// b1 @102400. Total 104448 B -> 256 blocks = 1/CU, ALL co-resident.
// Parity gate (target 128): even bid = low rows (live h, dead-byte stores);
// odd bid = high rows (ws copy, stores gated until low blocks signal).
// ---------------------------------------------------------------------------
__global__ __launch_bounds__(512, 2) void fused_mlp(
    const unsigned short* __restrict__ Hlo,
    const unsigned short* __restrict__ Hhi,
    const float* __restrict__ MU, const float* __restrict__ RS,
    const unsigned short* __restrict__ lw, const unsigned short* __restrict__ lb,
    const unsigned short* __restrict__ W1, const unsigned short* __restrict__ bs1,
    const unsigned short* __restrict__ W2, const unsigned short* __restrict__ bs2,
    void* __restrict__ OUT, const int* __restrict__ flagp,
    unsigned* __restrict__ gate)
{
  __shared__ __align__(16) unsigned char smem[104448];
  const int tid = threadIdx.x, lane = tid & 63, wave = tid >> 6;
  const int quad = lane >> 4, l16 = lane & 15;
  const int bid = blockIdx.x;
  const bool low = (bid & 1) == 0;
  const long grow = (low ? 0L : 32768L) + (long)(bid >> 1) * 256;
  const unsigned short* hbase = low ? (Hlo + (size_t)grow * 256)
                                    : (Hhi + ((size_t)grow - 32768) * 256);

  auto stageW1 = [&](int c, int sl) {
    const unsigned short* src = W1 + (size_t)c * 8192;   // 32 hid-rows x 256
    unsigned char* dst = smem + sl * 16384;
    #pragma unroll
    for (int s = 0; s < 2; s++) {
      const int unit = s * 512 + tid;
      const int row = unit >> 5, u = unit & 31;
      gl_lds16(src + row * 256 + ((u ^ (row & 7)) * 8), dst + unit * 16);
    }
  };
  auto stageW2 = [&](int c, int sl) {
    const unsigned short* src = W2 + c * 32;             // 256 rows x 32 (of 1024)
    unsigned char* dst = smem + 49152 + sl * 16384;
    #pragma unroll
    for (int s = 0; s < 2; s++) {
      const int unit = s * 512 + tid;
      const int row = unit >> 2, u = unit & 3;
      gl_lds16(src + (size_t)row * 1024 + ((u ^ ((row >> 1) & 3)) * 8), dst + unit * 16);
    }
  };

  // b1 -> LDS once (2 KB)
  unsigned short* b1l = (unsigned short*)(smem + 102400);
  if (tid < 128) *(u16x8*)&b1l[tid * 8] = *(const u16x8*)&bs1[tid * 8];

  // ---- LN2(h) A-fragments in registers, 2 row-groups:
  bf8 areg[2][8];
  #pragma unroll
  for (int rg = 0; rg < 2; rg++) {
    const int myrow = wave * 32 + rg * 16 + l16;
    const float m_ = MU[grow + myrow], r_ = RS[grow + myrow];
    const unsigned short* hr = hbase + (size_t)myrow * 256 + quad * 8;
    #pragma unroll
    for (int ks = 0; ks < 8; ks++) {
      u16x8 hv = *(const u16x8*)&hr[ks * 32];
      u16x8 wv = *(const u16x8*)&lw[ks * 32 + quad * 8];
      u16x8 bv = *(const u16x8*)&lb[ks * 32 + quad * 8];
      u16x8 o;
      #pragma unroll
      for (int e = 0; e < 8; e++)
        o[e] = f2b((b2f(hv[e]) - m_) * r_ * b2f(wv[e]) + b2f(bv[e]));
      *(u16x8*)&areg[rg][ks] = o;
    }
  }
  asm volatile("s_waitcnt vmcnt(0) lgkmcnt(0)" ::: "memory");  // areg/b1l done

  // ---- prologue staging: chunk 0 + chunk 1 (4+4 issues)
  stageW1(0, 0); stageW2(0, 0);
  stageW1(1, 1); stageW2(1, 1);
  asm volatile("s_waitcnt vmcnt(4)" ::: "memory");   // chunk-0 W landed (mine)
  __builtin_amdgcn_s_barrier();                      // (all)
  __builtin_amdgcn_sched_barrier(0);

  // ---- GEMM1(0): tT[32 hid x 32 tok] = W1(0) @ lnA^T  -> p regs
  f32x4 p00 = {}, p01 = {}, p10 = {}, p11 = {};
  {
    const unsigned short* w1b = (const unsigned short*)smem;
    #pragma unroll
    for (int ks = 0; ks < 8; ks++) {
      const int slot = (ks * 4 + quad) ^ (l16 & 7);
      bf8 a0, a1;
      *(u16x8*)&a0 = *(const u16x8*)&w1b[l16 * 256 + slot * 8];
      *(u16x8*)&a1 = *(const u16x8*)&w1b[(16 + l16) * 256 + slot * 8];
      p00 = __builtin_amdgcn_mfma_f32_16x16x32_bf16(a0, areg[0][ks], p00, 0, 0, 0);
      p01 = __builtin_amdgcn_mfma_f32_16x16x32_bf16(a0, areg[1][ks], p01, 0, 0, 0);
      p10 = __builtin_amdgcn_mfma_f32_16x16x32_bf16(a1, areg[0][ks], p10, 0, 0, 0);
      p11 = __builtin_amdgcn_mfma_f32_16x16x32_bf16(a1, areg[1][ks], p11, 0, 0, 0);
    }
  }

  f32x4 acc[2][16] = {};
  unsigned short* tw = (unsigned short*)(smem + 81920 + wave * 2560);
  const int gsw = (l16 >> 1) & 3;                    // W2 read swizzle

  for (int c = 0; c < 32; ++c) {
    if (c + 2 < 32) stageW1(c + 2, (c + 2) % 3);

    // ---- bias + GELU on chunk c (p from prev GEMM1); t[tok][hid] str 40 u16
    {
      u16x4 bv0 = *(const u16x4*)&b1l[c * 32 + quad * 4];
      u16x4 bv1 = *(const u16x4*)&b1l[c * 32 + 16 + quad * 4];
      u16x4 o00, o01, o10, o11;
      #pragma unroll
      for (int r = 0; r < 4; r++) {
        o00[r] = f2b(gelu_fast(p00[r] + b2f(bv0[r])));
        o01[r] = f2b(gelu_fast(p01[r] + b2f(bv0[r])));
        o10[r] = f2b(gelu_fast(p10[r] + b2f(bv1[r])));
        o11[r] = f2b(gelu_fast(p11[r] + b2f(bv1[r])));
      }
      *(u16x4*)&tw[l16 * 40 + quad * 4]             = o00;   // rg0, hid 0-15
      *(u16x4*)&tw[(16 + l16) * 40 + quad * 4]      = o01;   // rg1, hid 0-15
      *(u16x4*)&tw[l16 * 40 + 16 + quad * 4]        = o10;   // rg0, hid 16-31
      *(u16x4*)&tw[(16 + l16) * 40 + 16 + quad * 4] = o11;   // rg1, hid 16-31
    }
    asm volatile("s_waitcnt lgkmcnt(0)" ::: "memory");   // t visible (intra-wave)
    __builtin_amdgcn_sched_barrier(0);

    // ---- GEMM2(c): acc[rg][j] += t @ W2(c)^T   (W2 slot c&1)
    {
      bf8 ta0, ta1;
      *(u16x8*)&ta0 = *(const u16x8*)&tw[l16 * 40 + quad * 8];
      *(u16x8*)&ta1 = *(const u16x8*)&tw[(16 + l16) * 40 + quad * 8];
      const unsigned short* w2b = (const unsigned short*)(smem + 49152 + (c & 1) * 16384);
      #pragma unroll
      for (int j = 0; j < 16; j++) {
        bf8 bw;
        *(u16x8*)&bw = *(const u16x8*)&w2b[(j * 16 + l16) * 32 + ((quad ^ gsw) * 8)];
        acc[0][j] = __builtin_amdgcn_mfma_f32_16x16x32_bf16(ta0, bw, acc[0][j], 0, 0, 0);
        acc[1][j] = __builtin_amdgcn_mfma_f32_16x16x32_bf16(ta1, bw, acc[1][j], 0, 0, 0);
      }
    }

    // ---- wait W(c+1) landed (counted, never 0 mid-loop), then barrier
    if (c + 2 < 32) asm volatile("s_waitcnt vmcnt(2)" ::: "memory");
    else            asm volatile("s_waitcnt vmcnt(0)" ::: "memory");
    __builtin_amdgcn_s_barrier();
    __builtin_amdgcn_sched_barrier(0);

    // ---- post-barrier: restage W2(c+2) (slot c&1 now free for ALL waves),
    //      and GEMM1(c+1) from W1 slot (c+1)%3 -> p regs for next iter.
    if (c + 2 < 32) stageW2(c + 2, (c + 2) & 1);
    if (c + 1 < 32) {
      const unsigned short* w1b = (const unsigned short*)(smem + ((c + 1) % 3) * 16384);
      p00 = {}; p01 = {}; p10 = {}; p11 = {};
      #pragma unroll
      for (int ks = 0; ks < 8; ks++) {
        const int slot = (ks * 4 + quad) ^ (l16 & 7);
        bf8 a0, a1;
        *(u16x8*)&a0 = *(const u16x8*)&w1b[l16 * 256 + slot * 8];
        *(u16x8*)&a1 = *(const u16x8*)&w1b[(16 + l16) * 256 + slot * 8];
        p00 = __builtin_amdgcn_mfma_f32_16x16x32_bf16(a0, areg[0][ks], p00, 0, 0, 0);
        p01 = __builtin_amdgcn_mfma_f32_16x16x32_bf16(a0, areg[1][ks], p01, 0, 0, 0);
        p10 = __builtin_amdgcn_mfma_f32_16x16x32_bf16(a1, areg[0][ks], p10, 0, 0, 0);
        p11 = __builtin_amdgcn_mfma_f32_16x16x32_bf16(a1, areg[1][ks], p11, 0, 0, 0);
      }
    }
  }

  // ---- gate: high blocks must not write xup bytes until all low blocks
  //      have finished reading h.
  if (!low) {
    if (tid == 0) {
      while (__hip_atomic_load(gate, __ATOMIC_ACQUIRE, __HIP_MEMORY_SCOPE_AGENT) < 128u)
        __builtin_amdgcn_s_sleep(32);
    }
    __syncthreads();
  }

  // ---- epilogue: 4 quarters of 64 rows via cf [64][260] f32 (overlays ring)
  const bool obf = (*flagp) != 0;
  float* cf = (float*)smem;
  #pragma unroll
  for (int q = 0; q < 4; ++q) {
    __syncthreads();
    if ((wave >> 1) == q) {
      const int wl = (wave & 1) * 32;
      #pragma unroll
      for (int rg = 0; rg < 2; rg++)
        #pragma unroll
        for (int j = 0; j < 16; j++)
          #pragma unroll
          for (int r = 0; r < 4; r++)
            cf[(wl + rg * 16 + quad * 4 + r) * 260 + j * 16 + l16] = acc[rg][j][r];
    }
    __syncthreads();
    const unsigned short* hrow = hbase + (size_t)(q * 64) * 256;
    #pragma unroll
    for (int s = 0; s < 4; s++) {
      const int e = s * 4096 + tid * 8;
      const int row = e >> 8, col = e & 255;
      u16x8 rv = *(const u16x8*)&hrow[e];
      u16x8 b2v = *(const u16x8*)&bs2[col];
      float v[8];
      #pragma unroll
      for (int u = 0; u < 8; u++) v[u] = cf[row * 260 + col + u] + b2f(rv[u]) + b2f(b2v[u]);
      const size_t ob = (size_t)(grow + q * 64 + row) * 256 + col;
      if (obf) {
        u16x8 o;
        #pragma unroll
        for (int u = 0; u < 8; u++) o[u] = f2b(v[u]);
        *(u16x8*)&((unsigned short*)OUT)[ob] = o;
      } else {
        f32x4 oa, obv;
        oa[0]=v[0]; oa[1]=v[1]; oa[2]=v[2]; oa[3]=v[3];
        obv[0]=v[4]; obv[1]=v[5]; obv[2]=v[6]; obv[3]=v[7];
        *(f32x4*)&((float*)OUT)[ob] = oa;
        *(f32x4*)&((float*)OUT)[ob + 4] = obv;
      }
    }
  }

  // ---- low blocks signal: all their h reads are complete.
  if (low) {
    __syncthreads();
    if (tid == 0)
      __hip_atomic_fetch_add(gate, 1u, __ATOMIC_RELEASE, __HIP_MEMORY_SCOPE_AGENT);
  }
}

// ---------------------------------------------------------------------------
// accumG: per 256-token block k: partial G[h,s,d] = sum_n E[n,h*32+s]*X[n,h*32+d]
// (+ z partial at [8192+tid]). Batch b owns blocks k = b*32 .. b*32+31.
// ---------------------------------------------------------------------------
__global__ __launch_bounds__(256) void accumG(
    const unsigned short* __restrict__ X,
    const unsigned short* __restrict__ E,
    float* __restrict__ Gp)                 // [256][8448]
{
  __shared__ float Xl[64 * 256];                         // 64 KB
  __shared__ __align__(16) unsigned short El[64 * 256];  // 32 KB
  const int tid = threadIdx.x;
  const int k = blockIdx.x;
  const int h = tid >> 5, s = tid & 31;

  float acc[32];
  #pragma unroll
  for (int d = 0; d < 32; d++) acc[d] = 0.f;
  float zacc = 0.f;

  for (int sub = 0; sub < 4; sub++) {
    const size_t r0s = (size_t)k * 256 + sub * 64;
    __syncthreads();
    #pragma unroll
    for (int i = 0; i < 8; i++) {
      const int flat = i * 2048 + tid * 8;
      u16x8 xv = *(const u16x8*)&X[r0s * 256 + flat];
      #pragma unroll
      for (int e = 0; e < 8; e++) Xl[flat + e] = b2f(xv[e]);
      *(u16x8*)&El[flat] = *(const u16x8*)&E[r0s * 256 + flat];
    }
    __syncthreads();

    for (int t = 0; t < 64; t++) {
      const float e = b2f(El[t * 256 + h * 32 + s]);
      zacc += e;
      const int xb = t * 256 + h * 32;
      #pragma unroll
      for (int dq = 0; dq < 8; dq++) {
        f32x4 xv = *(const f32x4*)&Xl[xb + dq * 4];
        acc[dq*4+0] += e * xv[0];
        acc[dq*4+1] += e * xv[1];
        acc[dq*4+2] += e * xv[2];
        acc[dq*4+3] += e * xv[3];
      }
    }
  }

  float* gp = &Gp[(size_t)k * 8448 + (size_t)tid * 32];
  #pragma unroll
  for (int dq = 0; dq < 8; dq++) {
    f32x4 o; o[0]=acc[dq*4]; o[1]=acc[dq*4+1]; o[2]=acc[dq*4+2]; o[3]=acc[dq*4+3];
    *(f32x4*)&gp[dq * 4] = o;
  }
  Gp[(size_t)k * 8448 + 8192 + tid] = zacc;
}

// Gfin[b][j] = sum_{i<32} Gp[b*32+i][j], b in 0..7.
__global__ __launch_bounds__(256) void reduceG(const float* __restrict__ Gp,
                                               float* __restrict__ Gfin) {
  const int o = blockIdx.x * 256 + threadIdx.x;
  if (o >= 67584) return;
  const int b = o / 8448;
  const int j = o - b * 8448;
  float s = 0.f;
  #pragma unroll 8
  for (int i = 0; i < 32; i++) s += Gp[(size_t)(b * 32 + i) * 8448 + j];
  Gfin[o] = s;
}

// kv_build (8 blocks): kv[b,h,s,d] = (sum_dd G*Wv[d,dd]) / z; block-diag KVB.
__global__ __launch_bounds__(256) void kv_build(
    const float* __restrict__ Gfin, const unsigned short* __restrict__ Wv,
    unsigned short* __restrict__ KVB)
{
  __shared__ float Gl[8192];
  __shared__ float zl[256];
  __shared__ float wvt[1024];
  const int tid = threadIdx.x;
  const int b = blockIdx.x;
  for (int i = tid; i < 8192; i += 256) Gl[i] = Gfin[(size_t)b * 8448 + i];
  zl[tid] = Gfin[(size_t)b * 8448 + 8192 + tid];
  for (int i = tid; i < 1024; i += 256) {
    const int dd = i >> 5, d = i & 31;
    wvt[i] = b2f(Wv[d * 32 + dd]);
  }
  __syncthreads();

  const int h = tid >> 5, d = tid & 31;
  unsigned short row[32];
  for (int s = 0; s < 32; s++) {
    float a = 0.f;
    #pragma unroll
    for (int dd = 0; dd < 32; dd++) a += Gl[h * 1024 + s * 32 + dd] * wvt[dd * 32 + d];
    row[s] = f2b(a / zl[h * 32 + s]);
  }
  unsigned short* out = &KVB[(size_t)b * 65536 + (size_t)(h * 32 + d) * 256 + h * 32];
  #pragma unroll
  for (int e = 0; e < 4; e++) *(u16x8*)&out[e * 8] = *(u16x8*)&row[e * 8];
}

__global__ __launch_bounds__(256) void copy_h0(const unsigned short* __restrict__ src,
                                               unsigned short* __restrict__ dst) {
  size_t i = ((size_t)blockIdx.x * 256 + threadIdx.x) * 8;
  *(u16x8*)&dst[i] = *(const u16x8*)&src[i];
}

// ---------------------------------------------------------------------------
extern "C" void kernel_launch(void* const* d_in, const int* in_sizes, int n_in,
                              void* d_out, int out_size, void* d_ws, size_t ws_size,
                              hipStream_t stream)
{
  const void* fx   = d_in[0];
  const void* ln1w = d_in[1];
  const void* ln1b = d_in[2];
  const void* Wx   = d_in[3];
  const void* bx   = d_in[4];
  const void* Wq   = d_in[5];
  const void* Wk   = d_in[6];
  const void* Wv   = d_in[7];
  const void* Wo   = d_in[8];
  const void* bo   = d_in[9];
  const void* ln2w = d_in[10];
  const void* ln2b = d_in[11];
  const void* W1   = d_in[12];
  const void* b1   = d_in[13];
  const void* W2   = d_in[14];
  const void* b2   = d_in[15];

  // ws layout (~24.7 MB)
  unsigned short* ws    = (unsigned short*)d_ws;
  unsigned short* hid   = ws;                      // 8,388,608 u16 (16 MB): h-upper copy
  float* Gp             = (float*)ws;              // overlay: 256*8448 f32 (dead by MLP)
  unsigned short* wtab  = ws + 8388608;            // 661,248 u16
  unsigned short* h0res = wtab + 661248;           // 2,097,152 u16 (4 MB)
  float* Gfin           = (float*)h0res;           // overlay: 67,584 f32
  unsigned short* Wqbig = h0res + 2097152;         // 65,536
  unsigned short* Wkbig = Wqbig + 65536;           // 65,536
  unsigned short* KVB   = Wkbig + 65536;           // 524,288
  unsigned short* zbias = KVB + 524288;            // 256
  float* fpw = (float*)(zbias + 256);
  float* mu1 = fpw;
  float* rs1 = fpw + 65536;
  float* mu2 = fpw + 131072;
  float* rs2 = fpw + 196608;
  int* flagp = (int*)(fpw + 262144);
  unsigned* gatep = (unsigned*)(flagp + 1);

  const int OFF_LN1W=0, OFF_LN1B=256, OFF_WX=512, OFF_BX=66048,
            OFF_WQ=66304, OFF_WK=67328, OFF_WV=68352,
            OFF_WO=69376, OFF_BO=134912, OFF_LN2W=135168, OFF_LN2B=135424,
            OFF_W1=135680, OFF_B1=397824, OFF_W2=398848, OFF_B2=660992;

  unsigned short* xm  = (unsigned short*)d_out;    // lower: xmid->qkv2d (dead after Wo)
  unsigned short* xup = xm + 16777216;             // upper: E2d->QL->Qs->h

  // 0. dtype sniff + gate zero + weight table
  sniff_kernel<<<1, 64, 0, stream>>>((const unsigned*)fx, flagp, gatep);
  CvtDesc cd;
  const void* srcs[15] = {ln1w, ln1b, Wx, bx, Wq, Wk, Wv, Wo, bo, ln2w, ln2b, W1, b1, W2, b2};
  const int offs[15]   = {OFF_LN1W, OFF_LN1B, OFF_WX, OFF_BX, OFF_WQ, OFF_WK, OFF_WV,
                          OFF_WO, OFF_BO, OFF_LN2W, OFF_LN2B, OFF_W1, OFF_B1, OFF_W2, OFF_B2};
  const int ns[15]     = {256, 256, 65536, 256, 1024, 1024, 1024, 65536, 256, 256, 256,
                          262144, 1024, 262144, 256};
  for (int i = 0; i < 15; i++) { cd.src[i] = srcs[i]; cd.off[i] = offs[i]; cd.n[i] = ns[i]; }
  cvt_tab<<<dim3(1024, 15), 256, 0, stream>>>(cd, wtab, flagp);
  build_big<<<256, 256, 0, stream>>>(wtab + OFF_WQ, wtab + OFF_WK, Wqbig, Wkbig);
  zero_u16<<<257, 256, 0, stream>>>(KVB, 524544);

  // 1. LN1 stats; xmid = LN1(fx) @ Wx^T + bx -> xm
  ln_stats<<<16384, 256, 0, stream>>>(fx, flagp, 1, mu1, rs1);
  gemm_bt_ln<<<dim3(512, 2), 256, 0, stream>>>(fx, flagp, 1, mu1, rs1,
      wtab + OFF_LN1W, wtab + OFF_LN1B, wtab + OFF_WX, wtab + OFF_BX,
      xm, 256, 256, 0);

  // 2. E2d = exp(xmid @ Wkbig^T) -> xup
  gemm_bt<<<dim3(512, 2), 256, 0, stream>>>(xm, Wkbig, zbias, nullptr, flagp,
                                            xup, 256, 256, 2, 0, 0);

  // 3. G partials + reduce; kv -> KVB block-diag
  accumG<<<256, 256, 0, stream>>>(xm, xup, Gp);
  reduceG<<<264, 256, 0, stream>>>(Gp, Gfin);
  kv_build<<<8, 256, 0, stream>>>(Gfin, wtab + OFF_WV, KVB);

  // 4. Qs = segsoftmax(xmid @ Wqbig^T) -> xup (E2d dead), fused in epilogue
  gemm_bt<<<dim3(512, 2), 256, 0, stream>>>(xm, Wqbig, zbias, nullptr, flagp,
                                            xup, 256, 256, 3, 0, 0);

  // 5. qkv2d = Qs @ KVB[b]^T -> xm (xmid dead), z-batched over b
  gemm_bt<<<dim3(64, 2, 8), 256, 0, stream>>>(xup, KVB, zbias, nullptr, flagp,
                                              xm, 256, 256, 0, 8192, 65536);

  // 6. h = qkv2d @ Wo^T + bo + fx -> xup (Qs dead; NOT in-place -> full grid)
  gemm_bt<<<dim3(512, 2), 256, 0, stream>>>(xm, wtab + OFF_WO, wtab + OFF_BO, fx, flagp,
                                            xup, 256, 256, 0, 0, 0);

  // 7. LN2 stats on h; copy h rows [32768,65536) -> ws hid area (Gp dead).
  ln_stats<<<16384, 256, 0, stream>>>(xup, flagp, 0, mu2, rs2);
  copy_h0<<<4096, 256, 0, stream>>>(xup + (size_t)32768 * 256, hid);

  // 8. fused MLP: y = GELU(LN2(h)@W1^T+b1)@W2^T + b2 + h
  //    single 256-block launch (1 block/CU, all co-resident); even bid = low
  //    rows (live h, dead-byte stores), odd bid = high rows (copy h, gated).
  fused_mlp<<<256, 512, 0, stream>>>(xup, hid, mu2, rs2,
      wtab + OFF_LN2W, wtab + OFF_LN2B, wtab + OFF_W1, wtab + OFF_B1,
      wtab + OFF_W2, wtab + OFF_B2, d_out, flagp, gatep);
}